// Round 7
// baseline (152.778 us; speedup 1.0000x reference)
//
#include <hip/hip_runtime.h>

#define BB 4
#define CC 64
#define OO 64
#define HH 128
#define WW 128
#define HW (HH*WW)

#define TH 8            // output tile rows per block
#define TW 8            // output tile cols per block
#define WR 15           // staged window rows (tile + 3x3 reach + bilinear + ±2 offset margin)
#define WC 15           // staged window cols
#define NWIN (WR*WC)    // 225
#define PXS 36          // LDS dwords per window pixel (32 ch-pairs + 4 pad: stride ≡ 4 mod 32 rotates banks)

typedef __attribute__((ext_vector_type(8))) short short8;
typedef __attribute__((ext_vector_type(4))) float f32x4;

__device__ __forceinline__ unsigned f2b(float f) {  // RNE float->bf16 bits
  unsigned u = __float_as_uint(f);
  return (u + 0x7fffu + ((u >> 16) & 1u)) >> 16;
}
__device__ __forceinline__ float blo(unsigned r) { return __uint_as_float(r << 16); }
__device__ __forceinline__ float bhi(unsigned r) { return __uint_as_float(r & 0xffff0000u); }
__device__ __forceinline__ unsigned pk2(float a, float b) { return f2b(a) | (f2b(b) << 16); }

__device__ __forceinline__ short8 lerp8(uint4 q00, uint4 q01, uint4 q10, uint4 q11,
                                        float ww0, float ww1, float wh0, float wh1) {
  unsigned c00[4] = {q00.x, q00.y, q00.z, q00.w};
  unsigned c01[4] = {q01.x, q01.y, q01.z, q01.w};
  unsigned c10[4] = {q10.x, q10.y, q10.z, q10.w};
  unsigned c11[4] = {q11.x, q11.y, q11.z, q11.w};
  union { unsigned u[4]; short8 v; } A;
#pragma unroll
  for (int t = 0; t < 4; ++t) {
    float tL = fmaf(blo(c01[t]), ww1, blo(c00[t]) * ww0);
    float bL = fmaf(blo(c11[t]), ww1, blo(c10[t]) * ww0);
    float tH = fmaf(bhi(c01[t]), ww1, bhi(c00[t]) * ww0);
    float bH = fmaf(bhi(c11[t]), ww1, bhi(c10[t]) * ww0);
    A.u[t] = pk2(fmaf(bL, wh1, tL * wh0), fmaf(bH, wh1, tH * wh0));
  }
  return A.v;
}

// ---------------- weight repack to bf16, K-index = kk*64+c ----------------
__global__ __launch_bounds__(256) void repackw_kernel(const float* __restrict__ wt,
                                                      const float* __restrict__ ow,
                                                      ushort* __restrict__ wb,
                                                      ushort* __restrict__ owb) {
  int i = blockIdx.x * 256 + threadIdx.x;
  if (i < OO * 576) {
    int o = i / 576, r = i % 576;
    int kk = r >> 6, c = r & 63;
    wb[i] = (ushort)f2b(wt[(o * CC + c) * 9 + kk]);
  } else if (i < OO * 576 + 32 * 576) {
    int j = i - OO * 576;
    int oc = j / 576, r = j % 576;
    int kk = r >> 6, c = r & 63;
    owb[j] = (oc < 18) ? (ushort)f2b(ow[(oc * CC + c) * 9 + kk]) : (ushort)0;
  }
}

// fallback corner read straight from fp32 x (bf16-rounded, zero outside image)
// p0 = channel-pair base (s*16 + lq*4); returns 4 dwords = channels 2p0..2p0+7 at (r,c)
__device__ __forceinline__ uint4 gcorner(const float* __restrict__ xb, int p0, int r, int c) {
  uint4 v = make_uint4(0, 0, 0, 0);
  if (r >= 0 && r < HH && c >= 0 && c < WW) {
    const float* s = xb + ((size_t)2 * p0) * HW + r * WW + c;
    v.x = pk2(s[0], s[HW]);
    v.y = pk2(s[2 * HW], s[3 * HW]);
    v.z = pk2(s[4 * HW], s[5 * HW]);
    v.w = pk2(s[6 * HW], s[7 * HW]);
  }
  return v;
}

struct TapCtx { int h0, w0; float wh0, wh1, ww0, ww1; bool fastok; };

__device__ __forceinline__ TapCtx prep(int kh, int kw, float oh, float ow_,
                                       int h, int w, int rlo, int clo) {
  TapCtx t;
  float ph = (((float)kh + oh) + (float)h) + 1.0f;     // padded coords, ref op order
  float pw = (((float)kw + ow_) + (float)w) + 1.0f;
  ph = fminf(fmaxf(ph, 0.0f), 129.0f);
  pw = fminf(fmaxf(pw, 0.0f), 129.0f);
  float fh0 = floorf(ph), fw0 = floorf(pw);
  t.h0 = (int)fh0; t.w0 = (int)fw0;
  t.wh1 = ph - fh0; t.ww1 = pw - fw0;
  t.wh0 = 1.0f - t.wh1; t.ww0 = 1.0f - t.ww1;
  int wr0 = t.h0 - rlo, wc0 = t.w0 - clo;
  t.fastok = (wr0 >= 0) & (wr0 <= WR - 2) & (wc0 >= 0) & (wc0 <= WC - 2);
  return t;
}

__device__ __forceinline__ void load8_lds(uint4 q[8], const unsigned* __restrict__ win,
                                          const TapCtx& t, int rlo, int clo, int lq) {
  const unsigned* pA = &win[((t.h0 - rlo) * WC + (t.w0 - clo)) * PXS + lq * 4];
  q[0] = *(const uint4*)pA;
  q[1] = *(const uint4*)(pA + PXS);
  q[2] = *(const uint4*)(pA + WC * PXS);
  q[3] = *(const uint4*)(pA + WC * PXS + PXS);
  q[4] = *(const uint4*)(pA + 16);
  q[5] = *(const uint4*)(pA + PXS + 16);
  q[6] = *(const uint4*)(pA + WC * PXS + 16);
  q[7] = *(const uint4*)(pA + WC * PXS + PXS + 16);
}

__device__ __forceinline__ void load8_glb(uint4 q[8], const float* __restrict__ xb,
                                          const TapCtx& t, int lq) {
  int r0 = t.h0 - 1, c0 = t.w0 - 1;        // x coords
  q[0] = gcorner(xb, lq * 4, r0, c0);
  q[1] = gcorner(xb, lq * 4, r0, c0 + 1);
  q[2] = gcorner(xb, lq * 4, r0 + 1, c0);
  q[3] = gcorner(xb, lq * 4, r0 + 1, c0 + 1);
  q[4] = gcorner(xb, 16 + lq * 4, r0, c0);
  q[5] = gcorner(xb, 16 + lq * 4, r0, c0 + 1);
  q[6] = gcorner(xb, 16 + lq * 4, r0 + 1, c0);
  q[7] = gcorner(xb, 16 + lq * 4, r0 + 1, c0 + 1);
}

// ---------------- fused: stage window from fp32 x -> offs GEMM -> deform GEMM ----------------
__global__ __launch_bounds__(256, 3) void fused_deform(const float* __restrict__ x,
                                                       const ushort* __restrict__ wb,
                                                       const ushort* __restrict__ owb,
                                                       const float* __restrict__ obias,
                                                       const float* __restrict__ bias,
                                                       float* __restrict__ out) {
  __shared__ __align__(16) unsigned win[NWIN * PXS];   // 32.4 KB
  __shared__ __align__(16) float obuf[64 * 20];        // 5.1 KB

  int tid = threadIdx.x;
  int blk0 = blockIdx.x;
  int xcd = blk0 & 7, i = blk0 >> 3;
  int s = xcd * 8 + (i >> 4);            // slab 0..63 = b*16 + ht (8 slabs per XCD)
  int b = s >> 4, ht = s & 15, wtile = i & 15;
  int H0 = ht * TH, W0 = wtile * TW;
  int rlo = H0 - 1, clo = W0 - 1;        // window origin, padded coords

  int wave = tid >> 6, lane = tid & 63, lm = lane & 15, lq = lane >> 4;
  const float* xb = x + (size_t)b * CC * HW;

  // ---- stage window straight from fp32 x (bf16 round + channel-pair pack) ----
  for (int q = tid; q < NWIN * 8; q += 256) {
    int px = q >> 3, c8 = q & 7;
    int r = px / WC, c = px % WC;
    int xr = rlo + r - 1, xc = clo + c - 1;     // x coords
    uint4 v = make_uint4(0, 0, 0, 0);
    if (xr >= 0 && xr < HH && xc >= 0 && xc < WW) {
      const float* sp = xb + ((size_t)c8 * 8) * HW + xr * WW + xc;
      v.x = pk2(sp[0], sp[HW]);
      v.y = pk2(sp[2 * HW], sp[3 * HW]);
      v.z = pk2(sp[4 * HW], sp[5 * HW]);
      v.w = pk2(sp[6 * HW], sp[7 * HW]);
    }
    *(uint4*)&win[px * PXS + c8 * 4] = v;
  }
  __syncthreads();

  int row = 2 * wave + (lm >> 3);        // tile-local pixel coords for lane lm
  int col = lm & 7;
  int h = H0 + row, w = W0 + col;

  // ---- offs GEMM: 18 offset channels for this wave's 16 px (static taps, in-window) ----
  {
    f32x4 oacc[2];
    oacc[0] = (f32x4)0.0f; oacc[1] = (f32x4)0.0f;
#pragma unroll
    for (int kk = 0; kk < 9; ++kk) {
      int kh = kk / 3, kw = kk % 3;
      int widx = (row + kh + 1) * WC + (col + kw + 1);
      const unsigned* wp0 = &win[widx * PXS + lq * 4];
      union { uint4 q; short8 v; } a0, a1;
      a0.q = *(const uint4*)wp0;
      a1.q = *(const uint4*)(wp0 + 16);
#pragma unroll
      for (int nt = 0; nt < 2; ++nt) {
        short8 b0 = *(const short8*)&owb[(size_t)(nt * 16 + lm) * 576 + kk * 64 + lq * 8];
        short8 b1 = *(const short8*)&owb[(size_t)(nt * 16 + lm) * 576 + kk * 64 + 32 + lq * 8];
        oacc[nt] = __builtin_amdgcn_mfma_f32_16x16x32_bf16(a0.v, b0, oacc[nt], 0, 0, 0);
        oacc[nt] = __builtin_amdgcn_mfma_f32_16x16x32_bf16(a1.v, b1, oacc[nt], 0, 0, 0);
      }
    }
#pragma unroll
    for (int nt = 0; nt < 2; ++nt) {
      int oc = nt * 16 + lm;
      if (oc < 18) {
        float bv = obias[oc];
        int idx = (oc < 9) ? (oc * 2) : ((oc - 9) * 2 + 1);
#pragma unroll
        for (int r2 = 0; r2 < 4; ++r2)
          obuf[(wave * 16 + lq * 4 + r2) * 20 + idx] = oacc[nt][r2] + bv;
      }
    }
  }
  __syncthreads();

  float orow[20];
  {
    const float* orp = &obuf[(wave * 16 + lm) * 20];
#pragma unroll
    for (int q = 0; q < 5; ++q) *(float4*)&orow[q * 4] = *(const float4*)(orp + q * 4);
  }

  // ---- deform GEMM with 1-deep tap pipeline (loads of tap k+1 before compute of tap k) ----
  f32x4 acc[4];
#pragma unroll
  for (int nt = 0; nt < 4; ++nt) acc[nt] = (f32x4)0.0f;

  TapCtx tc = prep(0, 0, orow[0], orow[1], h, w, rlo, clo);
  uint4 cur[8];
  if (__builtin_amdgcn_ballot_w64(tc.fastok) == ~0ull) load8_lds(cur, win, tc, rlo, clo, lq);
  else load8_glb(cur, xb, tc, lq);

#pragma unroll
  for (int kk = 0; kk < 9; ++kk) {
    TapCtx tn;
    uint4 nxt[8];
    if (kk < 8) {
      int k2 = kk + 1;
      tn = prep(k2 / 3, k2 % 3, orow[k2 * 2], orow[k2 * 2 + 1], h, w, rlo, clo);
      if (__builtin_amdgcn_ballot_w64(tn.fastok) == ~0ull) load8_lds(nxt, win, tn, rlo, clo, lq);
      else load8_glb(nxt, xb, tn, lq);
    }
    short8 A0v = lerp8(cur[0], cur[1], cur[2], cur[3], tc.ww0, tc.ww1, tc.wh0, tc.wh1);
    short8 A1v = lerp8(cur[4], cur[5], cur[6], cur[7], tc.ww0, tc.ww1, tc.wh0, tc.wh1);
#pragma unroll
    for (int nt = 0; nt < 4; ++nt) {
      short8 b0 = *(const short8*)&wb[(size_t)(nt * 16 + lm) * 576 + kk * 64 + lq * 8];
      short8 b1 = *(const short8*)&wb[(size_t)(nt * 16 + lm) * 576 + kk * 64 + 32 + lq * 8];
      acc[nt] = __builtin_amdgcn_mfma_f32_16x16x32_bf16(A0v, b0, acc[nt], 0, 0, 0);
      acc[nt] = __builtin_amdgcn_mfma_f32_16x16x32_bf16(A1v, b1, acc[nt], 0, 0, 0);
    }
    if (kk < 8) {
      tc = tn;
#pragma unroll
      for (int j = 0; j < 8; ++j) cur[j] = nxt[j];
    }
  }

  // ---- epilogue ----
  {
    int px0 = lq * 4;
    int hrow = H0 + 2 * wave + (px0 >> 3);
    int wcol = W0 + (px0 & 7);
#pragma unroll
    for (int nt = 0; nt < 4; ++nt) {
      int o = nt * 16 + lm;
      float bv = bias[o];
      float4 st = make_float4(acc[nt][0] + bv, acc[nt][1] + bv, acc[nt][2] + bv, acc[nt][3] + bv);
      *(float4*)(out + ((size_t)(b * OO + o) * HH + hrow) * WW + wcol) = st;
    }
  }
}

extern "C" void kernel_launch(void* const* d_in, const int* in_sizes, int n_in,
                              void* d_out, int out_size, void* d_ws, size_t ws_size,
                              hipStream_t stream) {
  const float* x        = (const float*)d_in[0];
  const float* weight   = (const float*)d_in[1];
  const float* bias     = (const float*)d_in[2];
  const float* offset_w = (const float*)d_in[3];
  const float* offset_b = (const float*)d_in[4];
  float* out = (float*)d_out;

  ushort* wb  = (ushort*)d_ws;             // 64*576 bf16
  ushort* owb = wb + (size_t)OO * 576;     // 32*576 bf16

  repackw_kernel<<<(OO * 576 + 32 * 576 + 255) / 256, 256, 0, stream>>>(weight, offset_w, wb, owb);
  fused_deform<<<1024, 256, 0, stream>>>(x, wb, owb, offset_b, bias, out);
}

// Round 8
// 139.494 us; speedup vs baseline: 1.0952x; 1.0952x over previous
//
#include <hip/hip_runtime.h>

#define BB 4
#define CC 64
#define OO 64
#define HH 128
#define WW 128
#define HP 131          // padded rows (0..130 valid)
#define WP 132          // padded row width
#define HW (HH*WW)

#define TH 8            // output tile rows per block
#define TW 8            // output tile cols per block
#define WR 15           // staged window rows (tile + 3x3 reach + bilinear + ±2 offset margin)
#define WC 15           // staged window cols
#define NWIN (WR*WC)    // 225
#define PXS 36          // LDS dwords per window pixel (32 ch-pairs + 4 pad)

typedef __attribute__((ext_vector_type(8))) short short8;
typedef __attribute__((ext_vector_type(4))) float f32x4;

__device__ __forceinline__ unsigned f2b(float f) {  // RNE float->bf16 bits
  unsigned u = __float_as_uint(f);
  return (u + 0x7fffu + ((u >> 16) & 1u)) >> 16;
}
__device__ __forceinline__ float blo(unsigned r) { return __uint_as_float(r << 16); }
__device__ __forceinline__ float bhi(unsigned r) { return __uint_as_float(r & 0xffff0000u); }
__device__ __forceinline__ unsigned pk2(float a, float b) { return f2b(a) | (f2b(b) << 16); }

__device__ __forceinline__ short8 lerp8(uint4 q00, uint4 q01, uint4 q10, uint4 q11,
                                        float ww0, float ww1, float wh0, float wh1) {
  unsigned c00[4] = {q00.x, q00.y, q00.z, q00.w};
  unsigned c01[4] = {q01.x, q01.y, q01.z, q01.w};
  unsigned c10[4] = {q10.x, q10.y, q10.z, q10.w};
  unsigned c11[4] = {q11.x, q11.y, q11.z, q11.w};
  union { unsigned u[4]; short8 v; } A;
#pragma unroll
  for (int t = 0; t < 4; ++t) {
    float tL = fmaf(blo(c01[t]), ww1, blo(c00[t]) * ww0);
    float bL = fmaf(blo(c11[t]), ww1, blo(c10[t]) * ww0);
    float tH = fmaf(bhi(c01[t]), ww1, bhi(c00[t]) * ww0);
    float bH = fmaf(bhi(c11[t]), ww1, bhi(c10[t]) * ww0);
    A.u[t] = pk2(fmaf(bL, wh1, tL * wh0), fmaf(bH, wh1, tH * wh0));
  }
  return A.v;
}

// ---------------- pad + bf16 + CHANNEL-LAST: xp[b][hp][wp][c2] (uint = ch pair) ----------------
__global__ __launch_bounds__(256) void pad_kernel(const float* __restrict__ x,
                                                  unsigned* __restrict__ xp) {
  int i = blockIdx.x * 256 + threadIdx.x;       // (b,hp,wp,c8)
  if (i >= BB * HP * WP * 8) return;
  int c8 = i & 7;
  int t = i >> 3;
  int wp = t % WP;
  int t2 = t / WP;
  int hp = t2 % HP;
  int b = t2 / HP;
  uint4 v = make_uint4(0, 0, 0, 0);
  if (hp >= 1 && hp <= HH && wp >= 1 && wp <= WW) {
    const float* s = x + (((size_t)(b * CC + c8 * 8)) * HH + (hp - 1)) * WW + (wp - 1);
    v.x = pk2(s[0], s[HW]);
    v.y = pk2(s[2 * HW], s[3 * HW]);
    v.z = pk2(s[4 * HW], s[5 * HW]);
    v.w = pk2(s[6 * HW], s[7 * HW]);
  }
  *(uint4*)(xp + (size_t)t * 32 + c8 * 4) = v;
}

// ---------------- weight repack to bf16, K-index = kk*64+c ----------------
__global__ __launch_bounds__(256) void repackw_kernel(const float* __restrict__ wt,
                                                      const float* __restrict__ ow,
                                                      ushort* __restrict__ wb,
                                                      ushort* __restrict__ owb) {
  int i = blockIdx.x * 256 + threadIdx.x;
  if (i < OO * 576) {
    int o = i / 576, r = i % 576;
    int kk = r >> 6, c = r & 63;
    wb[i] = (ushort)f2b(wt[(o * CC + c) * 9 + kk]);
  } else if (i < OO * 576 + 32 * 576) {
    int j = i - OO * 576;
    int oc = j / 576, r = j % 576;
    int kk = r >> 6, c = r & 63;
    owb[j] = (oc < 18) ? (ushort)f2b(ow[(oc * CC + c) * 9 + kk]) : (ushort)0;
  }
}

// ---------------- fused: stage window -> offs GEMM -> deform GEMM (phase-split) ----------------
__global__ __launch_bounds__(256, 3) void fused_deform(const unsigned* __restrict__ xp,
                                                       const ushort* __restrict__ wb,
                                                       const ushort* __restrict__ owb,
                                                       const float* __restrict__ obias,
                                                       const float* __restrict__ bias,
                                                       float* __restrict__ out) {
  __shared__ __align__(16) unsigned win[NWIN * PXS];   // 32.4 KB
  __shared__ __align__(16) float obuf[64 * 20];        // 5.1 KB

  int tid = threadIdx.x;
  int blk0 = blockIdx.x;
  int xcd = blk0 & 7, i = blk0 >> 3;
  int s = xcd * 8 + (i >> 4);            // slab 0..63 = b*16 + ht
  int b = s >> 4, ht = s & 15, wtile = i & 15;
  int H0 = ht * TH, W0 = wtile * TW;
  int rlo = H0 - 1, clo = W0 - 1;        // window origin, padded coords

  int wave = tid >> 6, lane = tid & 63, lm = lane & 15, lq = lane >> 4;
  const unsigned* xpb = xp + (size_t)b * (HP * WP * 32);

  // ---- stage window (coalesced uint4 from padded bf16 xp) ----
  for (int q = tid; q < NWIN * 8; q += 256) {
    int px = q >> 3, ch = q & 7;
    int r = px / WC, c = px % WC;
    int pr = rlo + r, pc = clo + c;
    uint4 v = make_uint4(0, 0, 0, 0);
    if (pr >= 0 && pr <= HP - 1 && pc >= 0 && pc <= WP - 2)
      v = *(const uint4*)(xpb + ((size_t)pr * WP + pc) * 32 + ch * 4);
    *(uint4*)&win[px * PXS + ch * 4] = v;
  }
  __syncthreads();

  int row = 2 * wave + (lm >> 3);        // tile-local pixel coords for lane lm
  int col = lm & 7;
  int h = H0 + row, w = W0 + col;

  // ---- offs GEMM, phase-split: A-frags first, then pure MFMA ----
  {
    short8 Ao0[9], Ao1[9];
#pragma unroll
    for (int kk = 0; kk < 9; ++kk) {
      int kh = kk / 3, kw = kk % 3;
      int widx = (row + kh + 1) * WC + (col + kw + 1);
      const unsigned* wp0 = &win[widx * PXS + lq * 4];
      Ao0[kk] = *(const short8*)wp0;
      Ao1[kk] = *(const short8*)(wp0 + 16);
    }
    f32x4 oacc[2];
    oacc[0] = (f32x4)0.0f; oacc[1] = (f32x4)0.0f;
#pragma unroll
    for (int nt = 0; nt < 2; ++nt) {
#pragma unroll
      for (int kk = 0; kk < 9; ++kk) {
        short8 b0 = *(const short8*)&owb[(size_t)(nt * 16 + lm) * 576 + kk * 64 + lq * 8];
        short8 b1 = *(const short8*)&owb[(size_t)(nt * 16 + lm) * 576 + kk * 64 + 32 + lq * 8];
        oacc[nt] = __builtin_amdgcn_mfma_f32_16x16x32_bf16(Ao0[kk], b0, oacc[nt], 0, 0, 0);
        oacc[nt] = __builtin_amdgcn_mfma_f32_16x16x32_bf16(Ao1[kk], b1, oacc[nt], 0, 0, 0);
      }
    }
#pragma unroll
    for (int nt = 0; nt < 2; ++nt) {
      int oc = nt * 16 + lm;
      if (oc < 18) {
        float bv = obias[oc];
        int idx = (oc < 9) ? (oc * 2) : ((oc - 9) * 2 + 1);
#pragma unroll
        for (int r2 = 0; r2 < 4; ++r2)
          obuf[(wave * 16 + lq * 4 + r2) * 20 + idx] = oacc[nt][r2] + bv;
      }
    }
  }
  __syncthreads();

  float orow[20];
  {
    const float* orp = &obuf[(wave * 16 + lm) * 20];
#pragma unroll
    for (int q = 0; q < 5; ++q) *(float4*)&orow[q * 4] = *(const float4*)(orp + q * 4);
  }

  f32x4 acc[4];
#pragma unroll
  for (int nt = 0; nt < 4; ++nt) acc[nt] = (f32x4)0.0f;

  // ---- Phase 0: are all 9 taps of all lanes inside the staged window? ----
  bool okall = true;
#pragma unroll
  for (int kk = 0; kk < 9; ++kk) {
    int kh = kk / 3, kw = kk % 3;
    float ph = (((float)kh + orow[kk * 2]) + (float)h) + 1.0f;
    float pw = (((float)kw + orow[kk * 2 + 1]) + (float)w) + 1.0f;
    ph = fminf(fmaxf(ph, 0.0f), 129.0f);
    pw = fminf(fmaxf(pw, 0.0f), 129.0f);
    int h0 = (int)floorf(ph), w0 = (int)floorf(pw);
    int wr0 = h0 - rlo, wc0 = w0 - clo;
    okall &= (wr0 >= 0) & (wr0 <= WR - 2) & (wc0 >= 0) & (wc0 <= WC - 2);
  }

  if (__builtin_amdgcn_ballot_w64(okall) == ~0ull) {
    // ---- Phase 1: branch-free gather+lerp of ALL taps into held A-frags ----
    short8 Af0[9], Af1[9];
#pragma unroll
    for (int kk = 0; kk < 9; ++kk) {
      int kh = kk / 3, kw = kk % 3;
      float ph = (((float)kh + orow[kk * 2]) + (float)h) + 1.0f;
      float pw = (((float)kw + orow[kk * 2 + 1]) + (float)w) + 1.0f;
      ph = fminf(fmaxf(ph, 0.0f), 129.0f);
      pw = fminf(fmaxf(pw, 0.0f), 129.0f);
      float fh0 = floorf(ph), fw0 = floorf(pw);
      int h0 = (int)fh0, w0 = (int)fw0;
      float wh1 = ph - fh0, ww1 = pw - fw0;
      float wh0 = 1.0f - wh1, ww0 = 1.0f - ww1;
      const unsigned* pA = &win[((h0 - rlo) * WC + (w0 - clo)) * PXS + lq * 4];
      uint4 q00a = *(const uint4*)pA;
      uint4 q01a = *(const uint4*)(pA + PXS);
      uint4 q10a = *(const uint4*)(pA + WC * PXS);
      uint4 q11a = *(const uint4*)(pA + WC * PXS + PXS);
      uint4 q00b = *(const uint4*)(pA + 16);
      uint4 q01b = *(const uint4*)(pA + PXS + 16);
      uint4 q10b = *(const uint4*)(pA + WC * PXS + 16);
      uint4 q11b = *(const uint4*)(pA + WC * PXS + PXS + 16);
      Af0[kk] = lerp8(q00a, q01a, q10a, q11a, ww0, ww1, wh0, wh1);
      Af1[kk] = lerp8(q00b, q01b, q10b, q11b, ww0, ww1, wh0, wh1);
    }
    // ---- Phase 2: pure GEMM, 72 MFMA, streaming L1-resident B ----
#pragma unroll
    for (int nt = 0; nt < 4; ++nt) {
#pragma unroll
      for (int kk = 0; kk < 9; ++kk) {
        short8 b0 = *(const short8*)&wb[(size_t)(nt * 16 + lm) * 576 + kk * 64 + lq * 8];
        short8 b1 = *(const short8*)&wb[(size_t)(nt * 16 + lm) * 576 + kk * 64 + 32 + lq * 8];
        acc[nt] = __builtin_amdgcn_mfma_f32_16x16x32_bf16(Af0[kk], b0, acc[nt], 0, 0, 0);
        acc[nt] = __builtin_amdgcn_mfma_f32_16x16x32_bf16(Af1[kk], b1, acc[nt], 0, 0, 0);
      }
    }
  } else {
    // ---- cold exact path (never taken for this data): per-tap, global xp gather ----
#pragma unroll 1
    for (int kk = 0; kk < 9; ++kk) {
      int kh = kk / 3, kw = kk % 3;
      float ph = (((float)kh + orow[kk * 2]) + (float)h) + 1.0f;
      float pw = (((float)kw + orow[kk * 2 + 1]) + (float)w) + 1.0f;
      ph = fminf(fmaxf(ph, 0.0f), 129.0f);
      pw = fminf(fmaxf(pw, 0.0f), 129.0f);
      float fh0 = floorf(ph), fw0 = floorf(pw);
      int h0 = (int)fh0, w0 = (int)fw0;
      float wh1 = ph - fh0, ww1 = pw - fw0;
      float wh0 = 1.0f - wh1, ww0 = 1.0f - ww1;
      const unsigned* pG = xpb + ((size_t)h0 * WP + w0) * 32 + lq * 4;
      uint4 q00a = *(const uint4*)pG;
      uint4 q01a = *(const uint4*)(pG + 32);
      uint4 q10a = *(const uint4*)(pG + WP * 32);
      uint4 q11a = *(const uint4*)(pG + WP * 32 + 32);
      uint4 q00b = *(const uint4*)(pG + 16);
      uint4 q01b = *(const uint4*)(pG + 48);
      uint4 q10b = *(const uint4*)(pG + WP * 32 + 16);
      uint4 q11b = *(const uint4*)(pG + WP * 32 + 48);
      short8 A0v = lerp8(q00a, q01a, q10a, q11a, ww0, ww1, wh0, wh1);
      short8 A1v = lerp8(q00b, q01b, q10b, q11b, ww0, ww1, wh0, wh1);
#pragma unroll
      for (int nt = 0; nt < 4; ++nt) {
        short8 b0 = *(const short8*)&wb[(size_t)(nt * 16 + lm) * 576 + kk * 64 + lq * 8];
        short8 b1 = *(const short8*)&wb[(size_t)(nt * 16 + lm) * 576 + kk * 64 + 32 + lq * 8];
        acc[nt] = __builtin_amdgcn_mfma_f32_16x16x32_bf16(A0v, b0, acc[nt], 0, 0, 0);
        acc[nt] = __builtin_amdgcn_mfma_f32_16x16x32_bf16(A1v, b1, acc[nt], 0, 0, 0);
      }
    }
  }

  // ---- epilogue ----
  {
    int px0 = lq * 4;
    int hrow = H0 + 2 * wave + (px0 >> 3);
    int wcol = W0 + (px0 & 7);
#pragma unroll
    for (int nt = 0; nt < 4; ++nt) {
      int o = nt * 16 + lm;
      float bv = bias[o];
      float4 st = make_float4(acc[nt][0] + bv, acc[nt][1] + bv, acc[nt][2] + bv, acc[nt][3] + bv);
      *(float4*)(out + ((size_t)(b * OO + o) * HH + hrow) * WW + wcol) = st;
    }
  }
}

extern "C" void kernel_launch(void* const* d_in, const int* in_sizes, int n_in,
                              void* d_out, int out_size, void* d_ws, size_t ws_size,
                              hipStream_t stream) {
  const float* x        = (const float*)d_in[0];
  const float* weight   = (const float*)d_in[1];
  const float* bias     = (const float*)d_in[2];
  const float* offset_w = (const float*)d_in[3];
  const float* offset_b = (const float*)d_in[4];
  float* out = (float*)d_out;

  unsigned* xp  = (unsigned*)d_ws;                         // 4*131*132*32 uints = 8.85 MB
  ushort* wb  = (ushort*)(xp + (size_t)BB * HP * WP * 32); // 64*576
  ushort* owb = wb + (size_t)OO * 576;                     // 32*576

  pad_kernel<<<(BB * HP * WP * 8 + 255) / 256, 256, 0, stream>>>(x, xp);
  repackw_kernel<<<(OO * 576 + 32 * 576 + 255) / 256, 256, 0, stream>>>(weight, offset_w, wb, owb);
  fused_deform<<<1024, 256, 0, stream>>>(xp, wb, owb, offset_b, bias, out);
}